// Round 4
// baseline (1185.230 us; speedup 1.0000x reference)
//
#include <hip/hip_runtime.h>

typedef unsigned short u16;
typedef __bf16 bf16x8 __attribute__((ext_vector_type(8)));
typedef unsigned short us8 __attribute__((ext_vector_type(8)));
typedef unsigned short us4 __attribute__((ext_vector_type(4)));
typedef float f32x4 __attribute__((ext_vector_type(4)));

typedef __attribute__((address_space(3))) unsigned int as3_uint;
typedef const __attribute__((address_space(1))) unsigned int as1_cuint;

__device__ __forceinline__ u16 f2bf(float f) {
    unsigned u = __float_as_uint(f);
    u += 0x7FFFu + ((u >> 16) & 1u);
    return (u16)(u >> 16);
}
__device__ __forceinline__ float bf2f(u16 h) {
    return __uint_as_float(((unsigned)h) << 16);
}
__device__ __forceinline__ bf16x8 ld8(const u16* p) {
    return __builtin_bit_cast(bf16x8, *(const us8*)p);
}
#define MFMA16(a, b, c) __builtin_amdgcn_mfma_f32_16x16x32_bf16(a, b, c, 0, 0, 0)

__device__ __forceinline__ void glds16(const void* g, void* l) {
    __builtin_amdgcn_global_load_lds((as1_cuint*)g, (as3_uint*)l, 16, 0, 0);
}

// ---------------- pad-mask dtype detection + per-batch length -------------
__global__ void detect_k(const unsigned* __restrict__ pm, int* __restrict__ len4) {
    __shared__ int isbool;
    const int t = threadIdx.x;
    if (t == 0) isbool = 0;
    __syncthreads();
    unsigned orv = pm[t] | pm[256 + t] | pm[512 + t] | pm[768 + t];
    if (orv & 0xFFFFFF00u) atomicOr(&isbool, 1);
    __syncthreads();
    const int w = t >> 6, l = t & 63;
    int cnt = 0;
    if (isbool) {
        const unsigned char* p8 = (const unsigned char*)pm;
        for (int i = l; i < 1024; i += 64) cnt += (p8[w * 1024 + i] == 0) ? 1 : 0;
    } else {
        for (int i = l; i < 1024; i += 64) cnt += (pm[w * 1024 + i] == 0u) ? 1 : 0;
    }
#pragma unroll
    for (int m = 1; m < 64; m <<= 1) cnt += __shfl_xor(cnt, m);
    if (l == 0) {
        int c = cnt;
        if (c < 1) c = 1;
        if (c > 1024) c = 1024;
        len4[w] = c;
    }
}

// ---------- all-layer weight f32 -> bf16 conversion (one launch) ----------
// grid (4608, 6): 8 f32 -> 8 bf16 per thread (16B us8 store, 1KB/wave).
// Per-layer dst: [qkvo 2359296 | w1 4718592 | w2 2359296] u16 = 9437184/layer.
// All segment boundaries divisible by 8 -> chunks never straddle sources.
__global__ __launch_bounds__(256) void conv_k(
    const float* __restrict__ Wq, const float* __restrict__ Wk,
    const float* __restrict__ Wv, const float* __restrict__ Wo,
    const float* __restrict__ W1, const float* __restrict__ W2,
    const float* __restrict__ bq, const float* __restrict__ bk,
    const float* __restrict__ bv,
    u16* __restrict__ wall, float* __restrict__ bqkv6) {
    const int lyr = blockIdx.y;
    const int idx = blockIdx.x * 256 + threadIdx.x;
    const size_t e = (size_t)idx * 8;
    const float* src;
    if (e < 2359296u) {
        int which = (int)(e / 589824u);
        size_t off = e % 589824u;
        const float* m = (which == 0) ? Wq : (which == 1) ? Wk : (which == 2) ? Wv : Wo;
        src = m + (size_t)lyr * 589824u + off;
    } else if (e < 7077888u) {
        src = W1 + (size_t)lyr * 4718592u + (e - 2359296u);
    } else {
        src = W2 + (size_t)lyr * 2359296u + (e - 7077888u);
    }
    u16* dst = wall + (size_t)lyr * 9437184u + e;
    float4 v0 = ((const float4*)src)[0];
    float4 v1 = ((const float4*)src)[1];
    us8 o;
    o[0] = f2bf(v0.x); o[1] = f2bf(v0.y); o[2] = f2bf(v0.z); o[3] = f2bf(v0.w);
    o[4] = f2bf(v1.x); o[5] = f2bf(v1.y); o[6] = f2bf(v1.z); o[7] = f2bf(v1.w);
    *(us8*)dst = o;
    if (idx < 2304) {
        float bb = (idx < 768) ? bq[lyr * 768 + idx]
                 : (idx < 1536) ? bk[lyr * 768 + idx - 768]
                                : bv[lyr * 768 + idx - 1536];
        bqkv6[lyr * 2304 + idx] = bb;
    }
}

// ---------------- LayerNorm (f32 in; bf16 or f32 out) ---------------------
template <int OUTF>
__global__ __launch_bounds__(256) void ln_k(const float* __restrict__ x,
                                            const float* __restrict__ gm,
                                            const float* __restrict__ bt,
                                            void* __restrict__ outp) {
    const int w = threadIdx.x >> 6, l = threadIdx.x & 63;
    const int row = blockIdx.x * 4 + w;
    const float4* xr = (const float4*)(x + (size_t)row * 768);
    float4 v[3];
    float s = 0.f, ss = 0.f;
#pragma unroll
    for (int i = 0; i < 3; ++i) {
        v[i] = xr[i * 64 + l];
        s += v[i].x + v[i].y + v[i].z + v[i].w;
        ss += v[i].x * v[i].x + v[i].y * v[i].y + v[i].z * v[i].z + v[i].w * v[i].w;
    }
#pragma unroll
    for (int m = 1; m < 64; m <<= 1) {
        s += __shfl_xor(s, m);
        ss += __shfl_xor(ss, m);
    }
    const float mean = s * (1.f / 768.f);
    float var = ss * (1.f / 768.f) - mean * mean;
    var = fmaxf(var, 0.f);
    const float rs = rsqrtf(var + 1e-5f);
    const float4* g4 = (const float4*)gm;
    const float4* b4 = (const float4*)bt;
#pragma unroll
    for (int i = 0; i < 3; ++i) {
        float4 gg = g4[i * 64 + l], bb = b4[i * 64 + l];
        float o0 = (v[i].x - mean) * rs * gg.x + bb.x;
        float o1 = (v[i].y - mean) * rs * gg.y + bb.y;
        float o2 = (v[i].z - mean) * rs * gg.z + bb.z;
        float o3 = (v[i].w - mean) * rs * gg.w + bb.w;
        if (OUTF) {
            ((float4*)outp)[(size_t)row * 192 + i * 64 + l] = make_float4(o0, o1, o2, o3);
        } else {
            us4 pk;
            pk[0] = f2bf(o0); pk[1] = f2bf(o1); pk[2] = f2bf(o2); pk[3] = f2bf(o3);
            ((us4*)outp)[(size_t)row * 192 + i * 64 + l] = pk;
        }
    }
}

// ------------- 8-phase 256-row GEMM body, K=768 (12 tiles, 6 iters) -------
template <int VAR, int NF, int CHAIN, int PRO>
__device__ __forceinline__ void g256_body(
    const u16* __restrict__ Ab, const u16* __restrict__ Bb0,
    const u16* __restrict__ Bb1,
    const u16* __restrict__ AbN, const u16* __restrict__ Bb0N,
    const u16* __restrict__ Bb1N,
    const float* __restrict__ bias, u16* __restrict__ outp,
    u16* __restrict__ vT, int ldout, int ncol0, int m0,
    u16 (&lds)[2][4][8192]) {
    const int tid = threadIdx.x;
    const int w = tid >> 6, l = tid & 63, ax = l & 15, gx = l >> 4;
    const int wr = w >> 2, wc = w & 3;
    const int K = 768;

    const int row0 = tid >> 2, cc0 = (tid & 3) ^ ((row0 >> 1) & 3);
    const int row1 = 128 + row0, cc1 = (tid & 3) ^ ((row1 >> 1) & 3);
    const size_t goA0 = (size_t)row0 * K + cc0 * 8;
    const size_t goA1 = (size_t)row1 * K + cc1 * 8;

    auto stage = [&](int u, int kt, int nxt) {
        const int kh = u & 1;
        const size_t koff = (size_t)kt * 64 + kh * 32;
        u16* d = (u16*)&lds[kt & 1][u][0];
        const u16* A_ = nxt ? AbN : Ab;
        const u16* B0_ = nxt ? Bb0N : Bb0;
        const u16* B1_ = nxt ? Bb1N : Bb1;
        if (u < 2) {
            glds16(A_ + goA0 + koff, d + tid * 8);
            glds16(A_ + goA1 + koff, d + (512 + tid) * 8);
        } else {
            glds16(B0_ + goA0 + koff, d + tid * 8);
            glds16(B1_ + goA1 + koff, d + (512 + tid) * 8);
        }
    };

    bf16x8 rav[4], rbv[NF];
    f32x4 acc[8][NF] = {};

    auto phase = [&](int buf, int q, int kh, int readB, int vm, int su, int skt,
                     int nxt) {
        if (vm == 8) asm volatile("s_waitcnt vmcnt(8)" ::: "memory");
        else if (vm == 4) asm volatile("s_waitcnt vmcnt(4)" ::: "memory");
        else if (vm == 0) asm volatile("s_waitcnt vmcnt(0)" ::: "memory");
        __builtin_amdgcn_s_barrier();
        if (readB) {
#pragma unroll
            for (int j = 0; j < NF; ++j) {
                int row;
                if (VAR == 0) row = wc * (16 * NF) + j * 16 + ax;
                else row = ((j >= NF / 2) ? 128 : 0) + wc * (8 * NF) +
                           (j % (NF / 2)) * 16 + ax;
                rbv[j] = ld8(&lds[buf][2 + kh][row * 32 + ((gx ^ ((row >> 1) & 3)) * 8)]);
            }
        }
#pragma unroll
        for (int mf = 0; mf < 4; ++mf) {
            int row = wr * 128 + q * 64 + mf * 16 + ax;
            rav[mf] = ld8(&lds[buf][kh][row * 32 + ((gx ^ ((row >> 1) & 3)) * 8)]);
        }
        if (su >= 0) stage(su, skt, nxt);
        asm volatile("s_waitcnt lgkmcnt(0)" ::: "memory");
        __builtin_amdgcn_sched_barrier(0);
        __builtin_amdgcn_s_setprio(1);
#pragma unroll
        for (int mf = 0; mf < 4; ++mf)
#pragma unroll
            for (int j = 0; j < NF; ++j)
                acc[q * 4 + mf][j] = MFMA16(rav[mf], rbv[j], acc[q * 4 + mf][j]);
        __builtin_amdgcn_s_setprio(0);
    };

    if (PRO) {
        stage(0, 0, 0); stage(2, 0, 0); stage(1, 0, 0);
        stage(3, 0, 0); stage(0, 1, 0); stage(2, 1, 0);
    }

#pragma unroll 1
    for (int t = 0; t < 5; ++t) {
        const int O = 2 * t + 1, E2 = 2 * t + 2, O2 = 2 * t + 3;
        phase(0, 0, 0, 1, 8, 1, O, 0);
        phase(0, 1, 0, 0, -1, 3, O, 0);
        phase(0, 0, 1, 1, 8, 0, E2, 0);
        phase(0, 1, 1, 0, -1, 2, E2, 0);
        phase(1, 0, 0, 1, 8, 1, E2, 0);
        phase(1, 1, 0, 0, -1, 3, E2, 0);
        phase(1, 0, 1, 1, 8, 0, O2, 0);
        phase(1, 1, 1, 0, -1, 2, O2, 0);
    }
    if (CHAIN) {
        phase(0, 0, 0, 1, 8, 1, 11, 0);
        phase(0, 1, 0, 0, -1, 3, 11, 0);
        phase(0, 0, 1, 1, 8, 0, 0, 1);
        phase(0, 1, 1, 0, -1, 2, 0, 1);
        phase(1, 0, 0, 1, 8, 1, 0, 1);
        phase(1, 1, 0, 0, -1, 3, 0, 1);
        phase(1, 0, 1, 1, 8, 0, 1, 1);
        phase(1, 1, 1, 0, -1, 2, 1, 1);
    } else {
        phase(0, 0, 0, 1, 8, 1, 11, 0);
        phase(0, 1, 0, 0, -1, 3, 11, 0);
        phase(0, 0, 1, 1, 8, -1, 0, 0);
        phase(0, 1, 1, 0, -1, -1, 0, 0);
        phase(1, 0, 0, 1, 4, -1, 0, 0);
        phase(1, 1, 0, 0, -1, -1, 0, 0);
        phase(1, 0, 1, 1, 0, -1, 0, 0);
        phase(1, 1, 1, 0, -1, -1, 0, 0);
    }

    const int rowb = m0 + wr * 128;
    if (VAR == 0) {
        if (ncol0 >= 1536) {
#pragma unroll
            for (int j = 0; j < NF; ++j) {
                const int col = ncol0 + wc * (16 * NF) + j * 16 + ax;
                const float bn = bias[col];
                u16* vcol = vT + (size_t)(col - 1536) * 4096;
#pragma unroll
                for (int am = 0; am < 8; ++am) {
                    const int rb_ = rowb + am * 16 + 4 * gx;
                    us4 pk;
#pragma unroll
                    for (int r = 0; r < 4; ++r) pk[r] = f2bf(acc[am][j][r] + bn);
                    *(us4*)(vcol + rb_) = pk;
                }
            }
        } else {
#pragma unroll
            for (int j = 0; j < NF; ++j) {
                const int col = ncol0 + wc * (16 * NF) + j * 16 + ax;
                const float bn = bias[col];
#pragma unroll
                for (int am = 0; am < 8; ++am) {
                    const int rb_ = rowb + am * 16 + 4 * gx;
#pragma unroll
                    for (int r = 0; r < 4; ++r)
                        outp[(size_t)(rb_ + r) * ldout + col] = f2bf(acc[am][j][r] + bn);
                }
            }
        }
    } else {
        const int P = NF / 2;
#pragma unroll
        for (int nf = 0; nf < NF / 2; ++nf) {
            const int col = ncol0 + wc * (16 * P) + nf * 16 + ax;
            const float bu_ = bias[col], bg_ = bias[3072 + col];
#pragma unroll
            for (int am = 0; am < 8; ++am) {
                const int rb_ = rowb + am * 16 + 4 * gx;
#pragma unroll
                for (int r = 0; r < 4; ++r) {
                    float uu = acc[am][nf][r] + bu_;
                    float gg = acc[am][P + nf][r] + bg_;
                    float gel = 0.5f * gg * (1.f + erff(gg * 0.70710678118f));
                    outp[(size_t)(rb_ + r) * ldout + col] = f2bf(uu * gel);
                }
            }
        }
    }
}

// QKV: 256x192 tiles, grid 192 (balanced single round). V -> vT transposed.
__global__ __launch_bounds__(512, 2) void qkv256_k(
    const u16* __restrict__ A, const u16* __restrict__ W,
    const float* __restrict__ bias, u16* __restrict__ outp,
    u16* __restrict__ vT) {
    __shared__ __align__(16) u16 lds[2][4][8192];
    const int bid = blockIdx.x;
    const int swz = (bid & 7) * 24 + (bid >> 3);
    const int nb = swz >> 4, mb = swz & 15;
    const int m0 = mb * 256;
    const u16* Ab = A + (size_t)m0 * 768;
    const u16* Bb0 = W + (size_t)(nb * 192) * 768;
    g256_body<0, 3, 0, 1>(Ab, Bb0, Bb0, nullptr, nullptr, nullptr,
                          bias, outp, vT, 2304, nb * 192, m0, lds);
}

// FFN1: grid 256, perfectly balanced; each block = one full 256x128-geglu
// tile + one 256x64-geglu half tile, pipeline chained across the boundary.
__global__ __launch_bounds__(512, 2) void ffn1_k(
    const u16* __restrict__ A, const u16* __restrict__ W,
    const float* __restrict__ bias, u16* __restrict__ outp) {
    __shared__ __align__(16) u16 lds[2][4][8192];
    const int bid = blockIdx.x;
    const int swz = (bid & 7) * 32 + (bid >> 3);  // nwg=256
    const int nb = swz >> 4, mb = swz & 15;       // nb also = half-tile idx
    const int m0 = mb * 256;
    const u16* Ab = A + (size_t)m0 * 768;
    const u16* Bb0 = W + (size_t)(nb * 128) * 768;
    const u16* Bb1 = W + (size_t)(3072 + nb * 128 - 128) * 768;
    const u16* Bb0h = W + (size_t)(2048 + nb * 64) * 768;
    const u16* Bb1h = W + (size_t)(5120 + nb * 64 - 128) * 768;
    g256_body<1, 4, 1, 1>(Ab, Bb0, Bb1, Ab, Bb0h, Bb1h,
                          bias, outp, nullptr, 3072, nb * 128, m0, lds);
    g256_body<1, 2, 0, 0>(Ab, Bb0h, Bb1h, nullptr, nullptr, nullptr,
                          bias, outp, nullptr, 3072, 2048 + nb * 64, m0, lds);
}

// ----- 128x96 2-phase GEMM, 8 waves, wave-pair K-split (Wo / FFN2) --------
// Grid (N/96, M/128) = (8, 32) = 256 blocks -> perfectly balanced 1/CU.
// 8 waves = wr(2) x wc(2) x kz(2); kz owns one 32-wide half of each K-tile.
// Wave tile 64 rows x 48 cols, acc[4][3]. LDS 56KB (A 2x16KB, B 2x12KB).
// B staging: 96 rows = 768 chunks; waves 4-7 duplicate chunks 512-767 to the
// same LDS addrs (identical data) so every wave issues exactly 4 loads/stage
// and the vmcnt(4) discipline stays exact.
// kz-pair reduce through LDS float scratch, stride 49 (bank-conflict-free).
template <int EPI>
__global__ __launch_bounds__(512) void gemm_k(
    const u16* __restrict__ A, const u16* __restrict__ W,
    const float* __restrict__ bias, const float* __restrict__ resid,
    void* __restrict__ outp, int N, int K) {
    __shared__ __align__(16) u16 smem[2 * 8192 + 2 * 6144];  // 56KB
    const int tid = threadIdx.x;
    const int w = tid >> 6, l = tid & 63, a = l & 15, g = l >> 4;
    const int wr = w >> 2, wc = (w >> 1) & 1, kz = w & 1;
    const int m0 = blockIdx.y * 128, n0 = blockIdx.x * 96;
    f32x4 acc[4][3] = {};
    const int nk = K >> 6;

    auto stage = [&](int kt, int buf) {
        const int k0 = kt * 64;
        u16* dA = smem + buf * 8192;
        u16* dB = smem + 16384 + buf * 6144;
#pragma unroll
        for (int i = 0; i < 2; ++i) {
            int c = i * 512 + tid;
            int row = c >> 3, cc = c & 7, c8 = cc ^ (row & 7);
            glds16(A + (size_t)(m0 + row) * K + k0 + c8 * 8, dA + c * 8);
        }
        {
            int c = tid;  // B rows 0..63
            int row = c >> 3, cc = c & 7, c8 = cc ^ (row & 7);
            glds16(W + (size_t)(n0 + row) * K + k0 + c8 * 8, dB + c * 8);
        }
        {
            int c = 512 + (tid & 255);  // B rows 64..95 (waves 4-7 duplicate)
            int row = c >> 3, cc = c & 7, c8 = cc ^ (row & 7);
            glds16(W + (size_t)(n0 + row) * K + k0 + c8 * 8, dB + c * 8);
        }
    };

    stage(0, 0);
    int cur = 0;
    for (int kt = 0; kt < nk; ++kt) {
        if (kt + 1 < nk) {
            stage(kt + 1, cur ^ 1);
            __builtin_amdgcn_sched_barrier(0);
            asm volatile("s_waitcnt vmcnt(4)" ::: "memory");
        } else {
            __builtin_amdgcn_sched_barrier(0);
            asm volatile("s_waitcnt vmcnt(0)" ::: "memory");
        }
        __builtin_amdgcn_s_barrier();
        const u16* dA = smem + cur * 8192;
        const u16* dB = smem + 16384 + cur * 6144;
        bf16x8 af[4], bv_[3];
#pragma unroll
        for (int m = 0; m < 4; ++m) {
            int row = wr * 64 + m * 16 + a;
            af[m] = ld8(&dA[row * 64 + (((kz * 4 + g) ^ (a & 7)) * 8)]);
        }
#pragma unroll
        for (int n = 0; n < 3; ++n) {
            int row = wc * 48 + n * 16 + a;
            bv_[n] = ld8(&dB[row * 64 + (((kz * 4 + g) ^ (a & 7)) * 8)]);
        }
        asm volatile("s_waitcnt lgkmcnt(0)" ::: "memory");
        __builtin_amdgcn_sched_barrier(0);
        __builtin_amdgcn_s_setprio(1);
#pragma unroll
        for (int m = 0; m < 4; ++m)
#pragma unroll
            for (int n = 0; n < 3; ++n)
                acc[m][n] = MFMA16(af[m], bv_[n], acc[m][n]);
        __builtin_amdgcn_s_setprio(0);
        __builtin_amdgcn_s_barrier();
        cur ^= 1;
    }

    // kz-pair reduce through LDS scratch (stride 49: conflict-free)
    __syncthreads();
    float* sc = (float*)smem;
    const int quad = wr * 2 + wc;
    if (kz == 1) {
#pragma unroll
        for (int m = 0; m < 4; ++m)
#pragma unroll
            for (int n = 0; n < 3; ++n)
#pragma unroll
                for (int r = 0; r < 4; ++r)
                    sc[quad * 3136 + (m * 16 + 4 * g + r) * 49 + n * 16 + a] =
                        acc[m][n][r];
    }
    __syncthreads();
    if (kz == 0) {
        u16* outu = (u16*)outp;
        float* outf = (float*)outp;
        const int row0 = m0 + wr * 64, col0 = n0 + wc * 48;
#pragma unroll
        for (int n = 0; n < 3; ++n) {
            const int col = col0 + n * 16 + a;
            const float bn = bias[col];
#pragma unroll
            for (int m = 0; m < 4; ++m) {
                const int rb = row0 + m * 16 + 4 * g;
#pragma unroll
                for (int r = 0; r < 4; ++r) {
                    const size_t off = (size_t)(rb + r) * N + col;
                    float vv = acc[m][n][r] + bn +
                               sc[quad * 3136 + (m * 16 + 4 * g + r) * 49 + n * 16 + a];
                    if constexpr (EPI == 0) {
                        outu[off] = f2bf(vv);
                    } else {
                        outf[off] = vv + resid[off];
                    }
                }
            }
        }
    }
}

// ---------------- fused flash attention -----------------------------------
__global__ __launch_bounds__(256) void attn_k(const u16* __restrict__ qkv,
                                              const u16* __restrict__ vT,
                                              u16* __restrict__ av,
                                              const int* __restrict__ len4) {
    __shared__ __align__(16) u16 Ks[64 * 64];
    __shared__ __align__(16) u16 Vt[64 * 64];
    __shared__ __align__(16) u16 Ps[4][16 * 64];
    const int tid = threadIdx.x;
    const int w = tid >> 6, l = tid & 63, a = l & 15, g = l >> 4;
    const int qb = blockIdx.x, h = blockIdx.y, b = blockIdx.z;
    const size_t rowQ = (size_t)(b * 1024 + qb * 64 + w * 16 + a);
    const u16* qp = qkv + rowQ * 2304 + h * 64;
    bf16x8 qf[2];
    qf[0] = __builtin_bit_cast(bf16x8, *(const us8*)(qp + g * 8));
    qf[1] = __builtin_bit_cast(bf16x8, *(const us8*)(qp + 32 + g * 8));
    f32x4 O[4] = {};
    float m_r[4], l_r[4];
#pragma unroll
    for (int r = 0; r < 4; ++r) { m_r[r] = -1e30f; l_r[r] = 0.f; }
    const int length = len4[b];
    const int nkt = (length + 63) >> 6;
    for (int kt = 0; kt < nkt; ++kt) {
        __syncthreads();
#pragma unroll
        for (int i = 0; i < 2; ++i) {
            int c = i * 256 + tid;
            int row = c >> 3, cc = c & 7, c8 = cc ^ (row & 7);
            glds16(qkv + (size_t)(b * 1024 + kt * 64 + row) * 2304 + 768 + h * 64 + c8 * 8,
                   &Ks[c * 8]);
        }
        {
            const int d = l;
            const u16* vrow = vT + (size_t)(h * 64 + d) * 4096 + b * 1024 + kt * 64;
#pragma unroll
            for (int i = 0; i < 2; ++i) {
                int kkc = w + 4 * i;
                us8 vv = *(const us8*)(vrow + kkc * 8);
                int cc = kkc ^ (d & 7);
                *(us8*)&Vt[d * 64 + cc * 8] = vv;
            }
        }
        __syncthreads();
        f32x4 s[4] = {};
#pragma unroll
        for (int ks = 0; ks < 2; ++ks) {
#pragma unroll
            for (int f = 0; f < 4; ++f) {
                int row = f * 16 + a;
                bf16x8 kf = ld8(&Ks[row * 64 + (((ks * 4 + g) ^ (a & 7)) * 8)]);
                s[f] = MFMA16(qf[ks], kf, s[f]);
            }
        }
        float mloc[4] = {-1e30f, -1e30f, -1e30f, -1e30f};
#pragma unroll
        for (int f = 0; f < 4; ++f) {
            int kkg = kt * 64 + f * 16 + a;
            bool valid = kkg < length;
#pragma unroll
            for (int r = 0; r < 4; ++r) {
                float v = valid ? s[f][r] * 0.125f : -1e30f;
                s[f][r] = v;
                mloc[r] = fmaxf(mloc[r], v);
            }
        }
#pragma unroll
        for (int r = 0; r < 4; ++r) {
#pragma unroll
            for (int m = 1; m < 16; m <<= 1)
                mloc[r] = fmaxf(mloc[r], __shfl_xor(mloc[r], m));
        }
        float al[4], ps[4];
#pragma unroll
        for (int r = 0; r < 4; ++r) {
            float nm = fmaxf(m_r[r], mloc[r]);
            al[r] = __expf(m_r[r] - nm);
            m_r[r] = nm;
            ps[r] = 0.f;
        }
#pragma unroll
        for (int f = 0; f < 4; ++f)
#pragma unroll
            for (int r = 0; r < 4; ++r) {
                float p = __expf(s[f][r] - m_r[r]);
                s[f][r] = p;
                ps[r] += p;
            }
#pragma unroll
        for (int r = 0; r < 4; ++r) {
#pragma unroll
            for (int m = 1; m < 16; m <<= 1) ps[r] += __shfl_xor(ps[r], m);
            l_r[r] = l_r[r] * al[r] + ps[r];
        }
#pragma unroll
        for (int df = 0; df < 4; ++df)
#pragma unroll
            for (int r = 0; r < 4; ++r) O[df][r] *= al[r];
#pragma unroll
        for (int f = 0; f < 4; ++f)
#pragma unroll
            for (int r = 0; r < 4; ++r) {
                int prow = 4 * g + r;
                int cc = (2 * f + (a >> 3)) ^ (prow & 7);
                Ps[w][prow * 64 + cc * 8 + (a & 7)] = f2bf(s[f][r]);
            }
        asm volatile("s_waitcnt lgkmcnt(0)" ::: "memory");
        __builtin_amdgcn_sched_barrier(0);
#pragma unroll
        for (int ks = 0; ks < 2; ++ks) {
            bf16x8 pf = ld8(&Ps[w][a * 64 + (((ks * 4 + g) ^ (a & 7)) * 8)]);
#pragma unroll
            for (int df = 0; df < 4; ++df) {
                int vrow = df * 16 + a;
                bf16x8 vf = ld8(&Vt[vrow * 64 + (((ks * 4 + g) ^ (a & 7)) * 8)]);
                O[df] = MFMA16(pf, vf, O[df]);
            }
        }
    }
#pragma unroll
    for (int df = 0; df < 4; ++df) {
        int col = h * 64 + df * 16 + a;
#pragma unroll
        for (int r = 0; r < 4; ++r) {
            int row = b * 1024 + qb * 64 + w * 16 + 4 * g + r;
            av[(size_t)row * 768 + col] = f2bf(O[df][r] / l_r[r]);
        }
    }
}

// ---------------- host launcher -------------------------------------------
extern "C" void kernel_launch(void* const* d_in, const int* in_sizes, int n_in,
                              void* d_out, int out_size, void* d_ws, size_t ws_size,
                              hipStream_t stream) {
    const float* x_in = (const float*)d_in[0];
    const unsigned* pm = (const unsigned*)d_in[1];
    const float* Wq = (const float*)d_in[2];
    const float* bq = (const float*)d_in[3];
    const float* Wk = (const float*)d_in[4];
    const float* bk = (const float*)d_in[5];
    const float* Wv = (const float*)d_in[6];
    const float* bv = (const float*)d_in[7];
    const float* Wo = (const float*)d_in[8];
    const float* bo = (const float*)d_in[9];
    const float* g1 = (const float*)d_in[10];
    const float* be1 = (const float*)d_in[11];
    const float* g2 = (const float*)d_in[12];
    const float* be2 = (const float*)d_in[13];
    const float* W1 = (const float*)d_in[14];
    const float* b1 = (const float*)d_in[15];
    const float* W2 = (const float*)d_in[16];
    const float* b2 = (const float*)d_in[17];
    const float* og = (const float*)d_in[18];
    const float* ob = (const float*)d_in[19];

    char* ws = (char*)d_ws;
    u16* wall  = (u16*)(ws + 0);            // 6 layers x 9437184 u16 weights
    float* bqkv6 = (float*)(ws + 113246208);// [6][2304] f32
    int* len4  = (int*)(ws + 113301504);    // [4]
    float* xbuf = (float*)(ws + 113301760); // [4096][768] f32 residual stream
    u16* xn    = (u16*)(ws + 125884672);    // [4096][768] bf16
    u16* qkv   = (u16*)(ws + 132176128);    // [4096][2304] bf16 (V third unused)
    u16* avb   = (u16*)(ws + 151050496);    // [4096][768] bf16
    u16* ub    = (u16*)(ws + 157341952);    // [4096][3072] bf16
    u16* vT    = (u16*)(ws + 157341952);    // [768][4096] bf16, aliases ub
                                            // (vT live: qkv256 -> attn;
                                            //  ub live: ffn1 -> ffn2)

    detect_k<<<1, 256, 0, stream>>>(pm, len4);
    conv_k<<<dim3(4608, 6), 256, 0, stream>>>(Wq, Wk, Wv, Wo, W1, W2, bq, bk, bv,
                                              wall, bqkv6);
    for (int l = 0; l < 6; ++l) {
        u16* wl = wall + (size_t)l * 9437184u;
        const float* xcur = (l == 0) ? x_in : xbuf;
        ln_k<0><<<1024, 256, 0, stream>>>(xcur, g1 + l * 768, be1 + l * 768, xn);
        qkv256_k<<<192, 512, 0, stream>>>(xn, wl, bqkv6 + l * 2304, qkv, vT);
        attn_k<<<dim3(16, 12, 4), 256, 0, stream>>>(qkv, vT, avb, len4);
        gemm_k<1><<<dim3(8, 32), 512, 0, stream>>>(avb, wl + 3 * 589824, bo + l * 768,
                                                   xcur, xbuf, 768, 768);
        ln_k<0><<<1024, 256, 0, stream>>>(xbuf, g2 + l * 768, be2 + l * 768, xn);
        ffn1_k<<<256, 512, 0, stream>>>(xn, wl + 2359296, b1 + l * 6144, ub);
        gemm_k<1><<<dim3(8, 32), 512, 0, stream>>>(ub, wl + 7077888, b2 + l * 768, xbuf,
                                                   xbuf, 768, 3072);
    }
    ln_k<1><<<1024, 256, 0, stream>>>(xbuf, og, ob, d_out);
}

// Round 5
// 1179.994 us; speedup vs baseline: 1.0044x; 1.0044x over previous
//
#include <hip/hip_runtime.h>

typedef unsigned short u16;
typedef __bf16 bf16x8 __attribute__((ext_vector_type(8)));
typedef unsigned short us8 __attribute__((ext_vector_type(8)));
typedef unsigned short us4 __attribute__((ext_vector_type(4)));
typedef float f32x4 __attribute__((ext_vector_type(4)));

typedef __attribute__((address_space(3))) unsigned int as3_uint;
typedef const __attribute__((address_space(1))) unsigned int as1_cuint;

__device__ __forceinline__ u16 f2bf(float f) {
    unsigned u = __float_as_uint(f);
    u += 0x7FFFu + ((u >> 16) & 1u);
    return (u16)(u >> 16);
}
__device__ __forceinline__ float bf2f(u16 h) {
    return __uint_as_float(((unsigned)h) << 16);
}
__device__ __forceinline__ bf16x8 ld8(const u16* p) {
    return __builtin_bit_cast(bf16x8, *(const us8*)p);
}
#define MFMA16(a, b, c) __builtin_amdgcn_mfma_f32_16x16x32_bf16(a, b, c, 0, 0, 0)

__device__ __forceinline__ void glds16(const void* g, void* l) {
    __builtin_amdgcn_global_load_lds((as1_cuint*)g, (as3_uint*)l, 16, 0, 0);
}

// ---------------- pad-mask dtype detection + per-batch length -------------
__global__ void detect_k(const unsigned* __restrict__ pm, int* __restrict__ len4) {
    __shared__ int isbool;
    const int t = threadIdx.x;
    if (t == 0) isbool = 0;
    __syncthreads();
    unsigned orv = pm[t] | pm[256 + t] | pm[512 + t] | pm[768 + t];
    if (orv & 0xFFFFFF00u) atomicOr(&isbool, 1);
    __syncthreads();
    const int w = t >> 6, l = t & 63;
    int cnt = 0;
    if (isbool) {
        const unsigned char* p8 = (const unsigned char*)pm;
        for (int i = l; i < 1024; i += 64) cnt += (p8[w * 1024 + i] == 0) ? 1 : 0;
    } else {
        for (int i = l; i < 1024; i += 64) cnt += (pm[w * 1024 + i] == 0u) ? 1 : 0;
    }
#pragma unroll
    for (int m = 1; m < 64; m <<= 1) cnt += __shfl_xor(cnt, m);
    if (l == 0) {
        int c = cnt;
        if (c < 1) c = 1;
        if (c > 1024) c = 1024;
        len4[w] = c;
    }
}

// ---------- all-layer weight f32 -> bf16 conversion (one launch) ----------
// grid (9216, 6): blockIdx.y = layer; 4 f32/thread (16B load + 8B store).
// NOTE r4 lesson: 8 elems/thread (fewer threads, wider stores) REGRESSED
// 83 -> 90us; this kernel is MLP-limited, keep max thread count.
__global__ __launch_bounds__(256) void conv_k(
    const float* __restrict__ Wq, const float* __restrict__ Wk,
    const float* __restrict__ Wv, const float* __restrict__ Wo,
    const float* __restrict__ W1, const float* __restrict__ W2,
    const float* __restrict__ bq, const float* __restrict__ bk,
    const float* __restrict__ bv,
    u16* __restrict__ wall, float* __restrict__ bqkv6) {
    const int lyr = blockIdx.y;
    const int idx = blockIdx.x * 256 + threadIdx.x;
    const size_t e = (size_t)idx * 4;
    const float* src;
    if (e < 2359296u) {
        int which = (int)(e / 589824u);
        size_t off = e % 589824u;
        const float* m = (which == 0) ? Wq : (which == 1) ? Wk : (which == 2) ? Wv : Wo;
        src = m + (size_t)lyr * 589824u + off;
    } else if (e < 7077888u) {
        src = W1 + (size_t)lyr * 4718592u + (e - 2359296u);
    } else {
        src = W2 + (size_t)lyr * 2359296u + (e - 7077888u);
    }
    u16* dst = wall + (size_t)lyr * 9437184u + e;
    float4 v = *(const float4*)src;
    us4 o;
    o[0] = f2bf(v.x); o[1] = f2bf(v.y); o[2] = f2bf(v.z); o[3] = f2bf(v.w);
    *(us4*)dst = o;
    if (idx < 2304) {
        float bb = (idx < 768) ? bq[lyr * 768 + idx]
                 : (idx < 1536) ? bk[lyr * 768 + idx - 768]
                                : bv[lyr * 768 + idx - 1536];
        bqkv6[lyr * 2304 + idx] = bb;
    }
}

// ---------------- LayerNorm (f32 in; bf16 or f32 out) ---------------------
template <int OUTF>
__global__ __launch_bounds__(256) void ln_k(const float* __restrict__ x,
                                            const float* __restrict__ gm,
                                            const float* __restrict__ bt,
                                            void* __restrict__ outp) {
    const int w = threadIdx.x >> 6, l = threadIdx.x & 63;
    const int row = blockIdx.x * 4 + w;
    const float4* xr = (const float4*)(x + (size_t)row * 768);
    float4 v[3];
    float s = 0.f, ss = 0.f;
#pragma unroll
    for (int i = 0; i < 3; ++i) {
        v[i] = xr[i * 64 + l];
        s += v[i].x + v[i].y + v[i].z + v[i].w;
        ss += v[i].x * v[i].x + v[i].y * v[i].y + v[i].z * v[i].z + v[i].w * v[i].w;
    }
#pragma unroll
    for (int m = 1; m < 64; m <<= 1) {
        s += __shfl_xor(s, m);
        ss += __shfl_xor(ss, m);
    }
    const float mean = s * (1.f / 768.f);
    float var = ss * (1.f / 768.f) - mean * mean;
    var = fmaxf(var, 0.f);
    const float rs = rsqrtf(var + 1e-5f);
    const float4* g4 = (const float4*)gm;
    const float4* b4 = (const float4*)bt;
#pragma unroll
    for (int i = 0; i < 3; ++i) {
        float4 gg = g4[i * 64 + l], bb = b4[i * 64 + l];
        float o0 = (v[i].x - mean) * rs * gg.x + bb.x;
        float o1 = (v[i].y - mean) * rs * gg.y + bb.y;
        float o2 = (v[i].z - mean) * rs * gg.z + bb.z;
        float o3 = (v[i].w - mean) * rs * gg.w + bb.w;
        if (OUTF) {
            ((float4*)outp)[(size_t)row * 192 + i * 64 + l] = make_float4(o0, o1, o2, o3);
        } else {
            us4 pk;
            pk[0] = f2bf(o0); pk[1] = f2bf(o1); pk[2] = f2bf(o2); pk[3] = f2bf(o3);
            ((us4*)outp)[(size_t)row * 192 + i * 64 + l] = pk;
        }
    }
}

// ------------- 8-phase 256-row GEMM body, K=768 (12 tiles, 6 iters) -------
template <int VAR, int NF, int CHAIN, int PRO>
__device__ __forceinline__ void g256_body(
    const u16* __restrict__ Ab, const u16* __restrict__ Bb0,
    const u16* __restrict__ Bb1,
    const u16* __restrict__ AbN, const u16* __restrict__ Bb0N,
    const u16* __restrict__ Bb1N,
    const float* __restrict__ bias, u16* __restrict__ outp,
    u16* __restrict__ vT, int ldout, int ncol0, int m0,
    u16 (&lds)[2][4][8192]) {
    const int tid = threadIdx.x;
    const int w = tid >> 6, l = tid & 63, ax = l & 15, gx = l >> 4;
    const int wr = w >> 2, wc = w & 3;
    const int K = 768;

    const int row0 = tid >> 2, cc0 = (tid & 3) ^ ((row0 >> 1) & 3);
    const int row1 = 128 + row0, cc1 = (tid & 3) ^ ((row1 >> 1) & 3);
    const size_t goA0 = (size_t)row0 * K + cc0 * 8;
    const size_t goA1 = (size_t)row1 * K + cc1 * 8;

    auto stage = [&](int u, int kt, int nxt) {
        const int kh = u & 1;
        const size_t koff = (size_t)kt * 64 + kh * 32;
        u16* d = (u16*)&lds[kt & 1][u][0];
        const u16* A_ = nxt ? AbN : Ab;
        const u16* B0_ = nxt ? Bb0N : Bb0;
        const u16* B1_ = nxt ? Bb1N : Bb1;
        if (u < 2) {
            glds16(A_ + goA0 + koff, d + tid * 8);
            glds16(A_ + goA1 + koff, d + (512 + tid) * 8);
        } else {
            glds16(B0_ + goA0 + koff, d + tid * 8);
            glds16(B1_ + goA1 + koff, d + (512 + tid) * 8);
        }
    };

    bf16x8 rav[4], rbv[NF];
    f32x4 acc[8][NF] = {};

    auto phase = [&](int buf, int q, int kh, int readB, int vm, int su, int skt,
                     int nxt) {
        if (vm == 8) asm volatile("s_waitcnt vmcnt(8)" ::: "memory");
        else if (vm == 4) asm volatile("s_waitcnt vmcnt(4)" ::: "memory");
        else if (vm == 0) asm volatile("s_waitcnt vmcnt(0)" ::: "memory");
        __builtin_amdgcn_s_barrier();
        if (readB) {
#pragma unroll
            for (int j = 0; j < NF; ++j) {
                int row;
                if (VAR == 0) row = wc * (16 * NF) + j * 16 + ax;
                else row = ((j >= NF / 2) ? 128 : 0) + wc * (8 * NF) +
                           (j % (NF / 2)) * 16 + ax;
                rbv[j] = ld8(&lds[buf][2 + kh][row * 32 + ((gx ^ ((row >> 1) & 3)) * 8)]);
            }
        }
#pragma unroll
        for (int mf = 0; mf < 4; ++mf) {
            int row = wr * 128 + q * 64 + mf * 16 + ax;
            rav[mf] = ld8(&lds[buf][kh][row * 32 + ((gx ^ ((row >> 1) & 3)) * 8)]);
        }
        if (su >= 0) stage(su, skt, nxt);
        asm volatile("s_waitcnt lgkmcnt(0)" ::: "memory");
        __builtin_amdgcn_sched_barrier(0);
        __builtin_amdgcn_s_setprio(1);
#pragma unroll
        for (int mf = 0; mf < 4; ++mf)
#pragma unroll
            for (int j = 0; j < NF; ++j)
                acc[q * 4 + mf][j] = MFMA16(rav[mf], rbv[j], acc[q * 4 + mf][j]);
        __builtin_amdgcn_s_setprio(0);
    };

    if (PRO) {
        stage(0, 0, 0); stage(2, 0, 0); stage(1, 0, 0);
        stage(3, 0, 0); stage(0, 1, 0); stage(2, 1, 0);
    }

#pragma unroll 1
    for (int t = 0; t < 5; ++t) {
        const int O = 2 * t + 1, E2 = 2 * t + 2, O2 = 2 * t + 3;
        phase(0, 0, 0, 1, 8, 1, O, 0);
        phase(0, 1, 0, 0, -1, 3, O, 0);
        phase(0, 0, 1, 1, 8, 0, E2, 0);
        phase(0, 1, 1, 0, -1, 2, E2, 0);
        phase(1, 0, 0, 1, 8, 1, E2, 0);
        phase(1, 1, 0, 0, -1, 3, E2, 0);
        phase(1, 0, 1, 1, 8, 0, O2, 0);
        phase(1, 1, 1, 0, -1, 2, O2, 0);
    }
    if (CHAIN) {
        phase(0, 0, 0, 1, 8, 1, 11, 0);
        phase(0, 1, 0, 0, -1, 3, 11, 0);
        phase(0, 0, 1, 1, 8, 0, 0, 1);
        phase(0, 1, 1, 0, -1, 2, 0, 1);
        phase(1, 0, 0, 1, 8, 1, 0, 1);
        phase(1, 1, 0, 0, -1, 3, 0, 1);
        phase(1, 0, 1, 1, 8, 0, 1, 1);
        phase(1, 1, 1, 0, -1, 2, 1, 1);
    } else {
        phase(0, 0, 0, 1, 8, 1, 11, 0);
        phase(0, 1, 0, 0, -1, 3, 11, 0);
        phase(0, 0, 1, 1, 8, -1, 0, 0);
        phase(0, 1, 1, 0, -1, -1, 0, 0);
        phase(1, 0, 0, 1, 4, -1, 0, 0);
        phase(1, 1, 0, 0, -1, -1, 0, 0);
        phase(1, 0, 1, 1, 0, -1, 0, 0);
        phase(1, 1, 1, 0, -1, -1, 0, 0);
    }

    const int rowb = m0 + wr * 128;
    if (VAR == 0) {
        if (ncol0 >= 1536) {
#pragma unroll
            for (int j = 0; j < NF; ++j) {
                const int col = ncol0 + wc * (16 * NF) + j * 16 + ax;
                const float bn = bias[col];
                u16* vcol = vT + (size_t)(col - 1536) * 4096;
#pragma unroll
                for (int am = 0; am < 8; ++am) {
                    const int rb_ = rowb + am * 16 + 4 * gx;
                    us4 pk;
#pragma unroll
                    for (int r = 0; r < 4; ++r) pk[r] = f2bf(acc[am][j][r] + bn);
                    *(us4*)(vcol + rb_) = pk;
                }
            }
        } else {
#pragma unroll
            for (int j = 0; j < NF; ++j) {
                const int col = ncol0 + wc * (16 * NF) + j * 16 + ax;
                const float bn = bias[col];
#pragma unroll
                for (int am = 0; am < 8; ++am) {
                    const int rb_ = rowb + am * 16 + 4 * gx;
#pragma unroll
                    for (int r = 0; r < 4; ++r)
                        outp[(size_t)(rb_ + r) * ldout + col] = f2bf(acc[am][j][r] + bn);
                }
            }
        }
    } else {
        const int P = NF / 2;
#pragma unroll
        for (int nf = 0; nf < NF / 2; ++nf) {
            const int col = ncol0 + wc * (16 * P) + nf * 16 + ax;
            const float bu_ = bias[col], bg_ = bias[3072 + col];
#pragma unroll
            for (int am = 0; am < 8; ++am) {
                const int rb_ = rowb + am * 16 + 4 * gx;
#pragma unroll
                for (int r = 0; r < 4; ++r) {
                    float uu = acc[am][nf][r] + bu_;
                    float gg = acc[am][P + nf][r] + bg_;
                    float gel = 0.5f * gg * (1.f + erff(gg * 0.70710678118f));
                    outp[(size_t)(rb_ + r) * ldout + col] = f2bf(uu * gel);
                }
            }
        }
    }
}

// QKV: 256x192 tiles, grid 192 (balanced single round). V -> vT transposed.
__global__ __launch_bounds__(512, 2) void qkv256_k(
    const u16* __restrict__ A, const u16* __restrict__ W,
    const float* __restrict__ bias, u16* __restrict__ outp,
    u16* __restrict__ vT) {
    __shared__ __align__(16) u16 lds[2][4][8192];
    const int bid = blockIdx.x;
    const int swz = (bid & 7) * 24 + (bid >> 3);
    const int nb = swz >> 4, mb = swz & 15;
    const int m0 = mb * 256;
    const u16* Ab = A + (size_t)m0 * 768;
    const u16* Bb0 = W + (size_t)(nb * 192) * 768;
    g256_body<0, 3, 0, 1>(Ab, Bb0, Bb0, nullptr, nullptr, nullptr,
                          bias, outp, vT, 2304, nb * 192, m0, lds);
}

// FFN1: grid 256, perfectly balanced; each block = one full 256x128-geglu
// tile + one 256x64-geglu half tile, pipeline chained across the boundary.
__global__ __launch_bounds__(512, 2) void ffn1_k(
    const u16* __restrict__ A, const u16* __restrict__ W,
    const float* __restrict__ bias, u16* __restrict__ outp) {
    __shared__ __align__(16) u16 lds[2][4][8192];
    const int bid = blockIdx.x;
    const int swz = (bid & 7) * 32 + (bid >> 3);  // nwg=256
    const int nb = swz >> 4, mb = swz & 15;       // nb also = half-tile idx
    const int m0 = mb * 256;
    const u16* Ab = A + (size_t)m0 * 768;
    const u16* Bb0 = W + (size_t)(nb * 128) * 768;
    const u16* Bb1 = W + (size_t)(3072 + nb * 128 - 128) * 768;
    const u16* Bb0h = W + (size_t)(2048 + nb * 64) * 768;
    const u16* Bb1h = W + (size_t)(5120 + nb * 64 - 128) * 768;
    g256_body<1, 4, 1, 1>(Ab, Bb0, Bb1, Ab, Bb0h, Bb1h,
                          bias, outp, nullptr, 3072, nb * 128, m0, lds);
    g256_body<1, 2, 0, 0>(Ab, Bb0h, Bb1h, nullptr, nullptr, nullptr,
                          bias, outp, nullptr, 3072, 2048 + nb * 64, m0, lds);
}

// ----- 128x96 2-phase GEMM, 8 waves, wave-pair K-split (Wo / FFN2) --------
template <int EPI>
__global__ __launch_bounds__(512) void gemm_k(
    const u16* __restrict__ A, const u16* __restrict__ W,
    const float* __restrict__ bias, const float* __restrict__ resid,
    void* __restrict__ outp, int N, int K) {
    __shared__ __align__(16) u16 smem[2 * 8192 + 2 * 6144];  // 56KB
    const int tid = threadIdx.x;
    const int w = tid >> 6, l = tid & 63, a = l & 15, g = l >> 4;
    const int wr = w >> 2, wc = (w >> 1) & 1, kz = w & 1;
    const int m0 = blockIdx.y * 128, n0 = blockIdx.x * 96;
    f32x4 acc[4][3] = {};
    const int nk = K >> 6;

    auto stage = [&](int kt, int buf) {
        const int k0 = kt * 64;
        u16* dA = smem + buf * 8192;
        u16* dB = smem + 16384 + buf * 6144;
#pragma unroll
        for (int i = 0; i < 2; ++i) {
            int c = i * 512 + tid;
            int row = c >> 3, cc = c & 7, c8 = cc ^ (row & 7);
            glds16(A + (size_t)(m0 + row) * K + k0 + c8 * 8, dA + c * 8);
        }
        {
            int c = tid;  // B rows 0..63
            int row = c >> 3, cc = c & 7, c8 = cc ^ (row & 7);
            glds16(W + (size_t)(n0 + row) * K + k0 + c8 * 8, dB + c * 8);
        }
        {
            int c = 512 + (tid & 255);  // B rows 64..95 (waves 4-7 duplicate)
            int row = c >> 3, cc = c & 7, c8 = cc ^ (row & 7);
            glds16(W + (size_t)(n0 + row) * K + k0 + c8 * 8, dB + c * 8);
        }
    };

    stage(0, 0);
    int cur = 0;
    for (int kt = 0; kt < nk; ++kt) {
        if (kt + 1 < nk) {
            stage(kt + 1, cur ^ 1);
            __builtin_amdgcn_sched_barrier(0);
            asm volatile("s_waitcnt vmcnt(4)" ::: "memory");
        } else {
            __builtin_amdgcn_sched_barrier(0);
            asm volatile("s_waitcnt vmcnt(0)" ::: "memory");
        }
        __builtin_amdgcn_s_barrier();
        const u16* dA = smem + cur * 8192;
        const u16* dB = smem + 16384 + cur * 6144;
        bf16x8 af[4], bv_[3];
#pragma unroll
        for (int m = 0; m < 4; ++m) {
            int row = wr * 64 + m * 16 + a;
            af[m] = ld8(&dA[row * 64 + (((kz * 4 + g) ^ (a & 7)) * 8)]);
        }
#pragma unroll
        for (int n = 0; n < 3; ++n) {
            int row = wc * 48 + n * 16 + a;
            bv_[n] = ld8(&dB[row * 64 + (((kz * 4 + g) ^ (a & 7)) * 8)]);
        }
        asm volatile("s_waitcnt lgkmcnt(0)" ::: "memory");
        __builtin_amdgcn_sched_barrier(0);
        __builtin_amdgcn_s_setprio(1);
#pragma unroll
        for (int m = 0; m < 4; ++m)
#pragma unroll
            for (int n = 0; n < 3; ++n)
                acc[m][n] = MFMA16(af[m], bv_[n], acc[m][n]);
        __builtin_amdgcn_s_setprio(0);
        __builtin_amdgcn_s_barrier();
        cur ^= 1;
    }

    // kz-pair reduce through LDS scratch (stride 49: conflict-free)
    __syncthreads();
    float* sc = (float*)smem;
    const int quad = wr * 2 + wc;
    if (kz == 1) {
#pragma unroll
        for (int m = 0; m < 4; ++m)
#pragma unroll
            for (int n = 0; n < 3; ++n)
#pragma unroll
                for (int r = 0; r < 4; ++r)
                    sc[quad * 3136 + (m * 16 + 4 * g + r) * 49 + n * 16 + a] =
                        acc[m][n][r];
    }
    __syncthreads();
    if (kz == 0) {
        u16* outu = (u16*)outp;
        float* outf = (float*)outp;
        const int row0 = m0 + wr * 64, col0 = n0 + wc * 48;
#pragma unroll
        for (int n = 0; n < 3; ++n) {
            const int col = col0 + n * 16 + a;
            const float bn = bias[col];
#pragma unroll
            for (int m = 0; m < 4; ++m) {
                const int rb = row0 + m * 16 + 4 * g;
#pragma unroll
                for (int r = 0; r < 4; ++r) {
                    const size_t off = (size_t)(rb + r) * N + col;
                    float vv = acc[m][n][r] + bn +
                               sc[quad * 3136 + (m * 16 + 4 * g + r) * 49 + n * 16 + a];
                    if constexpr (EPI == 0) {
                        outu[off] = f2bf(vv);
                    } else {
                        outf[off] = vv + resid[off];
                    }
                }
            }
        }
    }
}

// -------- fused flash attention, double-buffered K/V staging --------------
// Per kt: issue kt+1 K-glds16 + V-reg-loads at top (latency hidden under
// QK+softmax), vmcnt(0) + V ds_write after softmax, ONE barrier per iter.
__global__ __launch_bounds__(256) void attn_k(const u16* __restrict__ qkv,
                                              const u16* __restrict__ vT,
                                              u16* __restrict__ av,
                                              const int* __restrict__ len4) {
    __shared__ __align__(16) u16 Ks[2][64 * 64];
    __shared__ __align__(16) u16 Vt[2][64 * 64];
    __shared__ __align__(16) u16 Ps[4][16 * 64];
    const int tid = threadIdx.x;
    const int w = tid >> 6, l = tid & 63, a = l & 15, g = l >> 4;
    const int qb = blockIdx.x, h = blockIdx.y, b = blockIdx.z;
    const size_t rowQ = (size_t)(b * 1024 + qb * 64 + w * 16 + a);
    const u16* qp = qkv + rowQ * 2304 + h * 64;
    bf16x8 qf[2];
    qf[0] = __builtin_bit_cast(bf16x8, *(const us8*)(qp + g * 8));
    qf[1] = __builtin_bit_cast(bf16x8, *(const us8*)(qp + 32 + g * 8));
    f32x4 O[4] = {};
    float m_r[4], l_r[4];
#pragma unroll
    for (int r = 0; r < 4; ++r) { m_r[r] = -1e30f; l_r[r] = 0.f; }
    const int length = len4[b];
    const int nkt = (length + 63) >> 6;

    auto stageK = [&](int kt, int buf) {
#pragma unroll
        for (int i = 0; i < 2; ++i) {
            int c = i * 256 + tid;
            int row = c >> 3, cc = c & 7, c8 = cc ^ (row & 7);
            glds16(qkv + (size_t)(b * 1024 + kt * 64 + row) * 2304 + 768 + h * 64 + c8 * 8,
                   &Ks[buf][c * 8]);
        }
    };
    us8 vv[2];
    auto loadV = [&](int kt) {
        const u16* vrow = vT + (size_t)(h * 64 + l) * 4096 + b * 1024 + kt * 64;
#pragma unroll
        for (int i = 0; i < 2; ++i) vv[i] = *(const us8*)(vrow + (w + 4 * i) * 8);
    };
    auto writeV = [&](int buf) {
#pragma unroll
        for (int i = 0; i < 2; ++i) {
            int kkc = w + 4 * i;
            int cc = kkc ^ (l & 7);
            *(us8*)&Vt[buf][l * 64 + cc * 8] = vv[i];
        }
    };

    stageK(0, 0);
    loadV(0);
    asm volatile("s_waitcnt vmcnt(0)" ::: "memory");
    writeV(0);
    __syncthreads();
    int buf = 0;
    for (int kt = 0; kt < nkt; ++kt) {
        const bool pf = (kt + 1 < nkt);
        if (pf) { stageK(kt + 1, buf ^ 1); loadV(kt + 1); }
        f32x4 s[4] = {};
#pragma unroll
        for (int ks = 0; ks < 2; ++ks) {
#pragma unroll
            for (int f = 0; f < 4; ++f) {
                int row = f * 16 + a;
                bf16x8 kf = ld8(&Ks[buf][row * 64 + (((ks * 4 + g) ^ (a & 7)) * 8)]);
                s[f] = MFMA16(qf[ks], kf, s[f]);
            }
        }
        float mloc[4] = {-1e30f, -1e30f, -1e30f, -1e30f};
#pragma unroll
        for (int f = 0; f < 4; ++f) {
            int kkg = kt * 64 + f * 16 + a;
            bool valid = kkg < length;
#pragma unroll
            for (int r = 0; r < 4; ++r) {
                float v = valid ? s[f][r] * 0.125f : -1e30f;
                s[f][r] = v;
                mloc[r] = fmaxf(mloc[r], v);
            }
        }
#pragma unroll
        for (int r = 0; r < 4; ++r) {
#pragma unroll
            for (int m = 1; m < 16; m <<= 1)
                mloc[r] = fmaxf(mloc[r], __shfl_xor(mloc[r], m));
        }
        float al[4], ps[4];
#pragma unroll
        for (int r = 0; r < 4; ++r) {
            float nm = fmaxf(m_r[r], mloc[r]);
            al[r] = __expf(m_r[r] - nm);
            m_r[r] = nm;
            ps[r] = 0.f;
        }
#pragma unroll
        for (int f = 0; f < 4; ++f)
#pragma unroll
            for (int r = 0; r < 4; ++r) {
                float p = __expf(s[f][r] - m_r[r]);
                s[f][r] = p;
                ps[r] += p;
            }
#pragma unroll
        for (int r = 0; r < 4; ++r) {
#pragma unroll
            for (int m = 1; m < 16; m <<= 1) ps[r] += __shfl_xor(ps[r], m);
            l_r[r] = l_r[r] * al[r] + ps[r];
        }
#pragma unroll
        for (int df = 0; df < 4; ++df)
#pragma unroll
            for (int r = 0; r < 4; ++r) O[df][r] *= al[r];
        // drain kt+1 staging loads, land V into the back buffer
        if (pf) {
            asm volatile("s_waitcnt vmcnt(0)" ::: "memory");
            writeV(buf ^ 1);
        }
#pragma unroll
        for (int f = 0; f < 4; ++f)
#pragma unroll
            for (int r = 0; r < 4; ++r) {
                int prow = 4 * g + r;
                int cc = (2 * f + (a >> 3)) ^ (prow & 7);
                Ps[w][prow * 64 + cc * 8 + (a & 7)] = f2bf(s[f][r]);
            }
        asm volatile("s_waitcnt lgkmcnt(0)" ::: "memory");
        __builtin_amdgcn_sched_barrier(0);
#pragma unroll
        for (int ks = 0; ks < 2; ++ks) {
            bf16x8 pf_ = ld8(&Ps[w][a * 64 + (((ks * 4 + g) ^ (a & 7)) * 8)]);
#pragma unroll
            for (int df = 0; df < 4; ++df) {
                int vrow = df * 16 + a;
                bf16x8 vf = ld8(&Vt[buf][vrow * 64 + (((ks * 4 + g) ^ (a & 7)) * 8)]);
                O[df] = MFMA16(pf_, vf, O[df]);
            }
        }
        __syncthreads();
        buf ^= 1;
    }
#pragma unroll
    for (int df = 0; df < 4; ++df) {
        int col = h * 64 + df * 16 + a;
#pragma unroll
        for (int r = 0; r < 4; ++r) {
            int row = b * 1024 + qb * 64 + w * 16 + 4 * g + r;
            av[(size_t)row * 768 + col] = f2bf(O[df][r] / l_r[r]);
        }
    }
}

// ---------------- host launcher -------------------------------------------
extern "C" void kernel_launch(void* const* d_in, const int* in_sizes, int n_in,
                              void* d_out, int out_size, void* d_ws, size_t ws_size,
                              hipStream_t stream) {
    const float* x_in = (const float*)d_in[0];
    const unsigned* pm = (const unsigned*)d_in[1];
    const float* Wq = (const float*)d_in[2];
    const float* bq = (const float*)d_in[3];
    const float* Wk = (const float*)d_in[4];
    const float* bk = (const float*)d_in[5];
    const float* Wv = (const float*)d_in[6];
    const float* bv = (const float*)d_in[7];
    const float* Wo = (const float*)d_in[8];
    const float* bo = (const float*)d_in[9];
    const float* g1 = (const float*)d_in[10];
    const float* be1 = (const float*)d_in[11];
    const float* g2 = (const float*)d_in[12];
    const float* be2 = (const float*)d_in[13];
    const float* W1 = (const float*)d_in[14];
    const float* b1 = (const float*)d_in[15];
    const float* W2 = (const float*)d_in[16];
    const float* b2 = (const float*)d_in[17];
    const float* og = (const float*)d_in[18];
    const float* ob = (const float*)d_in[19];

    char* ws = (char*)d_ws;
    u16* wall  = (u16*)(ws + 0);            // 6 layers x 9437184 u16 weights
    float* bqkv6 = (float*)(ws + 113246208);// [6][2304] f32
    int* len4  = (int*)(ws + 113301504);    // [4]
    float* xbuf = (float*)(ws + 113301760); // [4096][768] f32 residual stream
    u16* xn    = (u16*)(ws + 125884672);    // [4096][768] bf16
    u16* qkv   = (u16*)(ws + 132176128);    // [4096][2304] bf16 (V third unused)
    u16* avb   = (u16*)(ws + 151050496);    // [4096][768] bf16
    u16* ub    = (u16*)(ws + 157341952);    // [4096][3072] bf16
    u16* vT    = (u16*)(ws + 157341952);    // [768][4096] bf16, aliases ub
                                            // (vT live: qkv256 -> attn;
                                            //  ub live: ffn1 -> ffn2)

    detect_k<<<1, 256, 0, stream>>>(pm, len4);
    conv_k<<<dim3(9216, 6), 256, 0, stream>>>(Wq, Wk, Wv, Wo, W1, W2, bq, bk, bv,
                                              wall, bqkv6);
    for (int l = 0; l < 6; ++l) {
        u16* wl = wall + (size_t)l * 9437184u;
        const float* xcur = (l == 0) ? x_in : xbuf;
        ln_k<0><<<1024, 256, 0, stream>>>(xcur, g1 + l * 768, be1 + l * 768, xn);
        qkv256_k<<<192, 512, 0, stream>>>(xn, wl, bqkv6 + l * 2304, qkv, vT);
        attn_k<<<dim3(16, 12, 4), 256, 0, stream>>>(qkv, vT, avb, len4);
        gemm_k<1><<<dim3(8, 32), 512, 0, stream>>>(avb, wl + 3 * 589824, bo + l * 768,
                                                   xcur, xbuf, 768, 768);
        ln_k<0><<<1024, 256, 0, stream>>>(xbuf, g2 + l * 768, be2 + l * 768, xn);
        ffn1_k<<<256, 512, 0, stream>>>(xn, wl + 2359296, b1 + l * 6144, ub);
        gemm_k<1><<<dim3(8, 32), 512, 0, stream>>>(ub, wl + 7077888, b2 + l * 768, xbuf,
                                                   xbuf, 768, 3072);
    }
    ln_k<1><<<1024, 256, 0, stream>>>(xbuf, og, ob, d_out);
}

// Round 6
// 1124.218 us; speedup vs baseline: 1.0543x; 1.0496x over previous
//
#include <hip/hip_runtime.h>

typedef unsigned short u16;
typedef __bf16 bf16x8 __attribute__((ext_vector_type(8)));
typedef unsigned short us8 __attribute__((ext_vector_type(8)));
typedef unsigned short us4 __attribute__((ext_vector_type(4)));
typedef float f32x4 __attribute__((ext_vector_type(4)));

typedef __attribute__((address_space(3))) unsigned int as3_uint;
typedef const __attribute__((address_space(1))) unsigned int as1_cuint;

__device__ __forceinline__ u16 f2bf(float f) {
    unsigned u = __float_as_uint(f);
    u += 0x7FFFu + ((u >> 16) & 1u);
    return (u16)(u >> 16);
}
__device__ __forceinline__ float bf2f(u16 h) {
    return __uint_as_float(((unsigned)h) << 16);
}
__device__ __forceinline__ bf16x8 ld8(const u16* p) {
    return __builtin_bit_cast(bf16x8, *(const us8*)p);
}
#define MFMA16(a, b, c) __builtin_amdgcn_mfma_f32_16x16x32_bf16(a, b, c, 0, 0, 0)

__device__ __forceinline__ void glds16(const void* g, void* l) {
    __builtin_amdgcn_global_load_lds((as1_cuint*)g, (as3_uint*)l, 16, 0, 0);
}

// ---------------- pad-mask dtype detection + per-batch length -------------
__global__ void detect_k(const unsigned* __restrict__ pm, int* __restrict__ len4) {
    __shared__ int isbool;
    const int t = threadIdx.x;
    if (t == 0) isbool = 0;
    __syncthreads();
    unsigned orv = pm[t] | pm[256 + t] | pm[512 + t] | pm[768 + t];
    if (orv & 0xFFFFFF00u) atomicOr(&isbool, 1);
    __syncthreads();
    const int w = t >> 6, l = t & 63;
    int cnt = 0;
    if (isbool) {
        const unsigned char* p8 = (const unsigned char*)pm;
        for (int i = l; i < 1024; i += 64) cnt += (p8[w * 1024 + i] == 0) ? 1 : 0;
    } else {
        for (int i = l; i < 1024; i += 64) cnt += (pm[w * 1024 + i] == 0u) ? 1 : 0;
    }
#pragma unroll
    for (int m = 1; m < 64; m <<= 1) cnt += __shfl_xor(cnt, m);
    if (l == 0) {
        int c = cnt;
        if (c < 1) c = 1;
        if (c > 1024) c = 1024;
        len4[w] = c;
    }
}

// ---------- layer-0 weight conversion + ALL layers' qkv biases ------------
// grid 9216 x 256 thr, 4 f32/thread (16B load + 8B store) -- proven pattern.
// Layers 1..5 are converted inside the previous layer's FFN2 launch (hidden
// under compute); this upfront kernel only handles layer 0.
__global__ __launch_bounds__(256) void conv0_k(
    const float* __restrict__ Wq, const float* __restrict__ Wk,
    const float* __restrict__ Wv, const float* __restrict__ Wo,
    const float* __restrict__ W1, const float* __restrict__ W2,
    const float* __restrict__ bq, const float* __restrict__ bk,
    const float* __restrict__ bv,
    u16* __restrict__ wall, float* __restrict__ bqkv6) {
    const int idx = blockIdx.x * 256 + threadIdx.x;
    const size_t e = (size_t)idx * 4;
    const float* src;
    if (e < 2359296u) {
        int which = (int)(e / 589824u);
        size_t off = e % 589824u;
        const float* m = (which == 0) ? Wq : (which == 1) ? Wk : (which == 2) ? Wv : Wo;
        src = m + off;
    } else if (e < 7077888u) {
        src = W1 + (e - 2359296u);
    } else {
        src = W2 + (e - 7077888u);
    }
    u16* dst = wall + e;
    float4 v = *(const float4*)src;
    us4 o;
    o[0] = f2bf(v.x); o[1] = f2bf(v.y); o[2] = f2bf(v.z); o[3] = f2bf(v.w);
    *(us4*)dst = o;
    if (idx < 2304) {
#pragma unroll
        for (int lyr = 0; lyr < 6; ++lyr) {
            float bb = (idx < 768) ? bq[lyr * 768 + idx]
                     : (idx < 1536) ? bk[lyr * 768 + idx - 768]
                                    : bv[lyr * 768 + idx - 1536];
            bqkv6[lyr * 2304 + idx] = bb;
        }
    }
}

// ---------------- LayerNorm (f32 in; bf16 or f32 out) ---------------------
template <int OUTF>
__global__ __launch_bounds__(256) void ln_k(const float* __restrict__ x,
                                            const float* __restrict__ gm,
                                            const float* __restrict__ bt,
                                            void* __restrict__ outp) {
    const int w = threadIdx.x >> 6, l = threadIdx.x & 63;
    const int row = blockIdx.x * 4 + w;
    const float4* xr = (const float4*)(x + (size_t)row * 768);
    float4 v[3];
    float s = 0.f, ss = 0.f;
#pragma unroll
    for (int i = 0; i < 3; ++i) {
        v[i] = xr[i * 64 + l];
        s += v[i].x + v[i].y + v[i].z + v[i].w;
        ss += v[i].x * v[i].x + v[i].y * v[i].y + v[i].z * v[i].z + v[i].w * v[i].w;
    }
#pragma unroll
    for (int m = 1; m < 64; m <<= 1) {
        s += __shfl_xor(s, m);
        ss += __shfl_xor(ss, m);
    }
    const float mean = s * (1.f / 768.f);
    float var = ss * (1.f / 768.f) - mean * mean;
    var = fmaxf(var, 0.f);
    const float rs = rsqrtf(var + 1e-5f);
    const float4* g4 = (const float4*)gm;
    const float4* b4 = (const float4*)bt;
#pragma unroll
    for (int i = 0; i < 3; ++i) {
        float4 gg = g4[i * 64 + l], bb = b4[i * 64 + l];
        float o0 = (v[i].x - mean) * rs * gg.x + bb.x;
        float o1 = (v[i].y - mean) * rs * gg.y + bb.y;
        float o2 = (v[i].z - mean) * rs * gg.z + bb.z;
        float o3 = (v[i].w - mean) * rs * gg.w + bb.w;
        if (OUTF) {
            ((float4*)outp)[(size_t)row * 192 + i * 64 + l] = make_float4(o0, o1, o2, o3);
        } else {
            us4 pk;
            pk[0] = f2bf(o0); pk[1] = f2bf(o1); pk[2] = f2bf(o2); pk[3] = f2bf(o3);
            ((us4*)outp)[(size_t)row * 192 + i * 64 + l] = pk;
        }
    }
}

// ------------- 8-phase 256-row GEMM body, K=768 (12 tiles, 6 iters) -------
template <int VAR, int NF, int CHAIN, int PRO>
__device__ __forceinline__ void g256_body(
    const u16* __restrict__ Ab, const u16* __restrict__ Bb0,
    const u16* __restrict__ Bb1,
    const u16* __restrict__ AbN, const u16* __restrict__ Bb0N,
    const u16* __restrict__ Bb1N,
    const float* __restrict__ bias, u16* __restrict__ outp,
    u16* __restrict__ vT, int ldout, int ncol0, int m0,
    u16 (&lds)[2][4][8192]) {
    const int tid = threadIdx.x;
    const int w = tid >> 6, l = tid & 63, ax = l & 15, gx = l >> 4;
    const int wr = w >> 2, wc = w & 3;
    const int K = 768;

    const int row0 = tid >> 2, cc0 = (tid & 3) ^ ((row0 >> 1) & 3);
    const int row1 = 128 + row0, cc1 = (tid & 3) ^ ((row1 >> 1) & 3);
    const size_t goA0 = (size_t)row0 * K + cc0 * 8;
    const size_t goA1 = (size_t)row1 * K + cc1 * 8;

    auto stage = [&](int u, int kt, int nxt) {
        const int kh = u & 1;
        const size_t koff = (size_t)kt * 64 + kh * 32;
        u16* d = (u16*)&lds[kt & 1][u][0];
        const u16* A_ = nxt ? AbN : Ab;
        const u16* B0_ = nxt ? Bb0N : Bb0;
        const u16* B1_ = nxt ? Bb1N : Bb1;
        if (u < 2) {
            glds16(A_ + goA0 + koff, d + tid * 8);
            glds16(A_ + goA1 + koff, d + (512 + tid) * 8);
        } else {
            glds16(B0_ + goA0 + koff, d + tid * 8);
            glds16(B1_ + goA1 + koff, d + (512 + tid) * 8);
        }
    };

    bf16x8 rav[4], rbv[NF];
    f32x4 acc[8][NF] = {};

    auto phase = [&](int buf, int q, int kh, int readB, int vm, int su, int skt,
                     int nxt) {
        if (vm == 8) asm volatile("s_waitcnt vmcnt(8)" ::: "memory");
        else if (vm == 4) asm volatile("s_waitcnt vmcnt(4)" ::: "memory");
        else if (vm == 0) asm volatile("s_waitcnt vmcnt(0)" ::: "memory");
        __builtin_amdgcn_s_barrier();
        if (readB) {
#pragma unroll
            for (int j = 0; j < NF; ++j) {
                int row;
                if (VAR == 0) row = wc * (16 * NF) + j * 16 + ax;
                else row = ((j >= NF / 2) ? 128 : 0) + wc * (8 * NF) +
                           (j % (NF / 2)) * 16 + ax;
                rbv[j] = ld8(&lds[buf][2 + kh][row * 32 + ((gx ^ ((row >> 1) & 3)) * 8)]);
            }
        }
#pragma unroll
        for (int mf = 0; mf < 4; ++mf) {
            int row = wr * 128 + q * 64 + mf * 16 + ax;
            rav[mf] = ld8(&lds[buf][kh][row * 32 + ((gx ^ ((row >> 1) & 3)) * 8)]);
        }
        if (su >= 0) stage(su, skt, nxt);
        asm volatile("s_waitcnt lgkmcnt(0)" ::: "memory");
        __builtin_amdgcn_sched_barrier(0);
        __builtin_amdgcn_s_setprio(1);
#pragma unroll
        for (int mf = 0; mf < 4; ++mf)
#pragma unroll
            for (int j = 0; j < NF; ++j)
                acc[q * 4 + mf][j] = MFMA16(rav[mf], rbv[j], acc[q * 4 + mf][j]);
        __builtin_amdgcn_s_setprio(0);
    };

    if (PRO) {
        stage(0, 0, 0); stage(2, 0, 0); stage(1, 0, 0);
        stage(3, 0, 0); stage(0, 1, 0); stage(2, 1, 0);
    }

#pragma unroll 1
    for (int t = 0; t < 5; ++t) {
        const int O = 2 * t + 1, E2 = 2 * t + 2, O2 = 2 * t + 3;
        phase(0, 0, 0, 1, 8, 1, O, 0);
        phase(0, 1, 0, 0, -1, 3, O, 0);
        phase(0, 0, 1, 1, 8, 0, E2, 0);
        phase(0, 1, 1, 0, -1, 2, E2, 0);
        phase(1, 0, 0, 1, 8, 1, E2, 0);
        phase(1, 1, 0, 0, -1, 3, E2, 0);
        phase(1, 0, 1, 1, 8, 0, O2, 0);
        phase(1, 1, 1, 0, -1, 2, O2, 0);
    }
    if (CHAIN) {
        phase(0, 0, 0, 1, 8, 1, 11, 0);
        phase(0, 1, 0, 0, -1, 3, 11, 0);
        phase(0, 0, 1, 1, 8, 0, 0, 1);
        phase(0, 1, 1, 0, -1, 2, 0, 1);
        phase(1, 0, 0, 1, 8, 1, 0, 1);
        phase(1, 1, 0, 0, -1, 3, 0, 1);
        phase(1, 0, 1, 1, 8, 0, 1, 1);
        phase(1, 1, 1, 0, -1, 2, 1, 1);
    } else {
        phase(0, 0, 0, 1, 8, 1, 11, 0);
        phase(0, 1, 0, 0, -1, 3, 11, 0);
        phase(0, 0, 1, 1, 8, -1, 0, 0);
        phase(0, 1, 1, 0, -1, -1, 0, 0);
        phase(1, 0, 0, 1, 4, -1, 0, 0);
        phase(1, 1, 0, 0, -1, -1, 0, 0);
        phase(1, 0, 1, 1, 0, -1, 0, 0);
        phase(1, 1, 1, 0, -1, -1, 0, 0);
    }

    const int rowb = m0 + wr * 128;
    if (VAR == 0) {
        if (ncol0 >= 1536) {
#pragma unroll
            for (int j = 0; j < NF; ++j) {
                const int col = ncol0 + wc * (16 * NF) + j * 16 + ax;
                const float bn = bias[col];
                u16* vcol = vT + (size_t)(col - 1536) * 4096;
#pragma unroll
                for (int am = 0; am < 8; ++am) {
                    const int rb_ = rowb + am * 16 + 4 * gx;
                    us4 pk;
#pragma unroll
                    for (int r = 0; r < 4; ++r) pk[r] = f2bf(acc[am][j][r] + bn);
                    *(us4*)(vcol + rb_) = pk;
                }
            }
        } else {
#pragma unroll
            for (int j = 0; j < NF; ++j) {
                const int col = ncol0 + wc * (16 * NF) + j * 16 + ax;
                const float bn = bias[col];
#pragma unroll
                for (int am = 0; am < 8; ++am) {
                    const int rb_ = rowb + am * 16 + 4 * gx;
#pragma unroll
                    for (int r = 0; r < 4; ++r)
                        outp[(size_t)(rb_ + r) * ldout + col] = f2bf(acc[am][j][r] + bn);
                }
            }
        }
    } else {
        const int P = NF / 2;
#pragma unroll
        for (int nf = 0; nf < NF / 2; ++nf) {
            const int col = ncol0 + wc * (16 * P) + nf * 16 + ax;
            const float bu_ = bias[col], bg_ = bias[3072 + col];
#pragma unroll
            for (int am = 0; am < 8; ++am) {
                const int rb_ = rowb + am * 16 + 4 * gx;
#pragma unroll
                for (int r = 0; r < 4; ++r) {
                    float uu = acc[am][nf][r] + bu_;
                    float gg = acc[am][P + nf][r] + bg_;
                    float gel = 0.5f * gg * (1.f + erff(gg * 0.70710678118f));
                    outp[(size_t)(rb_ + r) * ldout + col] = f2bf(uu * gel);
                }
            }
        }
    }
}

// QKV: 256x192 tiles, grid 192 (balanced single round). V -> vT transposed.
__global__ __launch_bounds__(512, 2) void qkv256_k(
    const u16* __restrict__ A, const u16* __restrict__ W,
    const float* __restrict__ bias, u16* __restrict__ outp,
    u16* __restrict__ vT) {
    __shared__ __align__(16) u16 lds[2][4][8192];
    const int bid = blockIdx.x;
    const int swz = (bid & 7) * 24 + (bid >> 3);
    const int nb = swz >> 4, mb = swz & 15;
    const int m0 = mb * 256;
    const u16* Ab = A + (size_t)m0 * 768;
    const u16* Bb0 = W + (size_t)(nb * 192) * 768;
    g256_body<0, 3, 0, 1>(Ab, Bb0, Bb0, nullptr, nullptr, nullptr,
                          bias, outp, vT, 2304, nb * 192, m0, lds);
}

// FFN1: grid 256, perfectly balanced; each block = one full 256x128-geglu
// tile + one 256x64-geglu half tile, pipeline chained across the boundary.
__global__ __launch_bounds__(512, 2) void ffn1_k(
    const u16* __restrict__ A, const u16* __restrict__ W,
    const float* __restrict__ bias, u16* __restrict__ outp) {
    __shared__ __align__(16) u16 lds[2][4][8192];
    const int bid = blockIdx.x;
    const int swz = (bid & 7) * 32 + (bid >> 3);  // nwg=256
    const int nb = swz >> 4, mb = swz & 15;       // nb also = half-tile idx
    const int m0 = mb * 256;
    const u16* Ab = A + (size_t)m0 * 768;
    const u16* Bb0 = W + (size_t)(nb * 128) * 768;
    const u16* Bb1 = W + (size_t)(3072 + nb * 128 - 128) * 768;
    const u16* Bb0h = W + (size_t)(2048 + nb * 64) * 768;
    const u16* Bb1h = W + (size_t)(5120 + nb * 64 - 128) * 768;
    g256_body<1, 4, 1, 1>(Ab, Bb0, Bb1, Ab, Bb0h, Bb1h,
                          bias, outp, nullptr, 3072, nb * 128, m0, lds);
    g256_body<1, 2, 0, 0>(Ab, Bb0h, Bb1h, nullptr, nullptr, nullptr,
                          bias, outp, nullptr, 3072, 2048 + nb * 64, m0, lds);
}

// ----- 128x96 2-phase GEMM, 8 waves, wave-pair K-split (Wo / FFN2) --------
// grid z>1 slices host next-layer weight conversion: conv blocks claim the
// same 56KB static LDS, so one conv block co-resides with the one compute
// block per CU (112KB <= 160KB, 16 <= 32 waves); z=0 blocks dispatch first,
// conv traffic soaks spare HBM bandwidth under the compute window.
template <int EPI>
__global__ __launch_bounds__(512) void gemm_k(
    const u16* __restrict__ A, const u16* __restrict__ W,
    const float* __restrict__ bias, const float* __restrict__ resid,
    void* __restrict__ outp, int N, int K,
    const float* __restrict__ cWq, const float* __restrict__ cWk,
    const float* __restrict__ cWv, const float* __restrict__ cWo,
    const float* __restrict__ cW1, const float* __restrict__ cW2,
    u16* __restrict__ cwall, int cvtlyr) {
    __shared__ __align__(16) u16 smem[2 * 8192 + 2 * 6144];  // 56KB
    if (blockIdx.z > 0) {
        // weight-conversion block for layer cvtlyr (18 slices x 256 blocks
        // x 512 thr x 4 elems = 9437184 elems exactly)
        const int cid = ((int)blockIdx.z - 1) * 256 + (int)blockIdx.y * 8 +
                        (int)blockIdx.x;
        const size_t e = ((size_t)cid * 512 + threadIdx.x) * 4;
        const float* src;
        if (e < 2359296u) {
            int which = (int)(e / 589824u);
            size_t off = e % 589824u;
            const float* m = (which == 0) ? cWq : (which == 1) ? cWk
                           : (which == 2) ? cWv : cWo;
            src = m + (size_t)cvtlyr * 589824u + off;
        } else if (e < 7077888u) {
            src = cW1 + (size_t)cvtlyr * 4718592u + (e - 2359296u);
        } else {
            src = cW2 + (size_t)cvtlyr * 2359296u + (e - 7077888u);
        }
        u16* dst = cwall + (size_t)cvtlyr * 9437184u + e;
        float4 v = *(const float4*)src;
        us4 o;
        o[0] = f2bf(v.x); o[1] = f2bf(v.y); o[2] = f2bf(v.z); o[3] = f2bf(v.w);
        *(us4*)dst = o;
        return;
    }
    const int tid = threadIdx.x;
    const int w = tid >> 6, l = tid & 63, a = l & 15, g = l >> 4;
    const int wr = w >> 2, wc = (w >> 1) & 1, kz = w & 1;
    const int m0 = blockIdx.y * 128, n0 = blockIdx.x * 96;
    f32x4 acc[4][3] = {};
    const int nk = K >> 6;

    auto stage = [&](int kt, int buf) {
        const int k0 = kt * 64;
        u16* dA = smem + buf * 8192;
        u16* dB = smem + 16384 + buf * 6144;
#pragma unroll
        for (int i = 0; i < 2; ++i) {
            int c = i * 512 + tid;
            int row = c >> 3, cc = c & 7, c8 = cc ^ (row & 7);
            glds16(A + (size_t)(m0 + row) * K + k0 + c8 * 8, dA + c * 8);
        }
        {
            int c = tid;  // B rows 0..63
            int row = c >> 3, cc = c & 7, c8 = cc ^ (row & 7);
            glds16(W + (size_t)(n0 + row) * K + k0 + c8 * 8, dB + c * 8);
        }
        {
            int c = 512 + (tid & 255);  // B rows 64..95 (waves 4-7 duplicate)
            int row = c >> 3, cc = c & 7, c8 = cc ^ (row & 7);
            glds16(W + (size_t)(n0 + row) * K + k0 + c8 * 8, dB + c * 8);
        }
    };

    stage(0, 0);
    int cur = 0;
    for (int kt = 0; kt < nk; ++kt) {
        if (kt + 1 < nk) {
            stage(kt + 1, cur ^ 1);
            __builtin_amdgcn_sched_barrier(0);
            asm volatile("s_waitcnt vmcnt(4)" ::: "memory");
        } else {
            __builtin_amdgcn_sched_barrier(0);
            asm volatile("s_waitcnt vmcnt(0)" ::: "memory");
        }
        __builtin_amdgcn_s_barrier();
        const u16* dA = smem + cur * 8192;
        const u16* dB = smem + 16384 + cur * 6144;
        bf16x8 af[4], bv_[3];
#pragma unroll
        for (int m = 0; m < 4; ++m) {
            int row = wr * 64 + m * 16 + a;
            af[m] = ld8(&dA[row * 64 + (((kz * 4 + g) ^ (a & 7)) * 8)]);
        }
#pragma unroll
        for (int n = 0; n < 3; ++n) {
            int row = wc * 48 + n * 16 + a;
            bv_[n] = ld8(&dB[row * 64 + (((kz * 4 + g) ^ (a & 7)) * 8)]);
        }
        asm volatile("s_waitcnt lgkmcnt(0)" ::: "memory");
        __builtin_amdgcn_sched_barrier(0);
        __builtin_amdgcn_s_setprio(1);
#pragma unroll
        for (int m = 0; m < 4; ++m)
#pragma unroll
            for (int n = 0; n < 3; ++n)
                acc[m][n] = MFMA16(af[m], bv_[n], acc[m][n]);
        __builtin_amdgcn_s_setprio(0);
        __builtin_amdgcn_s_barrier();
        cur ^= 1;
    }

    // kz-pair reduce through LDS scratch (stride 49: conflict-free)
    __syncthreads();
    float* sc = (float*)smem;
    const int quad = wr * 2 + wc;
    if (kz == 1) {
#pragma unroll
        for (int m = 0; m < 4; ++m)
#pragma unroll
            for (int n = 0; n < 3; ++n)
#pragma unroll
                for (int r = 0; r < 4; ++r)
                    sc[quad * 3136 + (m * 16 + 4 * g + r) * 49 + n * 16 + a] =
                        acc[m][n][r];
    }
    __syncthreads();
    if (kz == 0) {
        u16* outu = (u16*)outp;
        float* outf = (float*)outp;
        const int row0 = m0 + wr * 64, col0 = n0 + wc * 48;
#pragma unroll
        for (int n = 0; n < 3; ++n) {
            const int col = col0 + n * 16 + a;
            const float bn = bias[col];
#pragma unroll
            for (int m = 0; m < 4; ++m) {
                const int rb = row0 + m * 16 + 4 * g;
#pragma unroll
                for (int r = 0; r < 4; ++r) {
                    const size_t off = (size_t)(rb + r) * N + col;
                    float vv = acc[m][n][r] + bn +
                               sc[quad * 3136 + (m * 16 + 4 * g + r) * 49 + n * 16 + a];
                    if constexpr (EPI == 0) {
                        outu[off] = f2bf(vv);
                    } else {
                        outf[off] = vv + resid[off];
                    }
                }
            }
        }
    }
}

// -------- fused flash attention, double-buffered K/V staging --------------
__global__ __launch_bounds__(256) void attn_k(const u16* __restrict__ qkv,
                                              const u16* __restrict__ vT,
                                              u16* __restrict__ av,
                                              const int* __restrict__ len4) {
    __shared__ __align__(16) u16 Ks[2][64 * 64];
    __shared__ __align__(16) u16 Vt[2][64 * 64];
    __shared__ __align__(16) u16 Ps[4][16 * 64];
    const int tid = threadIdx.x;
    const int w = tid >> 6, l = tid & 63, a = l & 15, g = l >> 4;
    const int qb = blockIdx.x, h = blockIdx.y, b = blockIdx.z;
    const size_t rowQ = (size_t)(b * 1024 + qb * 64 + w * 16 + a);
    const u16* qp = qkv + rowQ * 2304 + h * 64;
    bf16x8 qf[2];
    qf[0] = __builtin_bit_cast(bf16x8, *(const us8*)(qp + g * 8));
    qf[1] = __builtin_bit_cast(bf16x8, *(const us8*)(qp + 32 + g * 8));
    f32x4 O[4] = {};
    float m_r[4], l_r[4];
#pragma unroll
    for (int r = 0; r < 4; ++r) { m_r[r] = -1e30f; l_r[r] = 0.f; }
    const int length = len4[b];
    const int nkt = (length + 63) >> 6;

    auto stageK = [&](int kt, int buf) {
#pragma unroll
        for (int i = 0; i < 2; ++i) {
            int c = i * 256 + tid;
            int row = c >> 3, cc = c & 7, c8 = cc ^ (row & 7);
            glds16(qkv + (size_t)(b * 1024 + kt * 64 + row) * 2304 + 768 + h * 64 + c8 * 8,
                   &Ks[buf][c * 8]);
        }
    };
    us8 vv[2];
    auto loadV = [&](int kt) {
        const u16* vrow = vT + (size_t)(h * 64 + l) * 4096 + b * 1024 + kt * 64;
#pragma unroll
        for (int i = 0; i < 2; ++i) vv[i] = *(const us8*)(vrow + (w + 4 * i) * 8);
    };
    auto writeV = [&](int buf) {
#pragma unroll
        for (int i = 0; i < 2; ++i) {
            int kkc = w + 4 * i;
            int cc = kkc ^ (l & 7);
            *(us8*)&Vt[buf][l * 64 + cc * 8] = vv[i];
        }
    };

    stageK(0, 0);
    loadV(0);
    asm volatile("s_waitcnt vmcnt(0)" ::: "memory");
    writeV(0);
    __syncthreads();
    int buf = 0;
    for (int kt = 0; kt < nkt; ++kt) {
        const bool pf = (kt + 1 < nkt);
        if (pf) { stageK(kt + 1, buf ^ 1); loadV(kt + 1); }
        f32x4 s[4] = {};
#pragma unroll
        for (int ks = 0; ks < 2; ++ks) {
#pragma unroll
            for (int f = 0; f < 4; ++f) {
                int row = f * 16 + a;
                bf16x8 kf = ld8(&Ks[buf][row * 64 + (((ks * 4 + g) ^ (a & 7)) * 8)]);
                s[f] = MFMA16(qf[ks], kf, s[f]);
            }
        }
        float mloc[4] = {-1e30f, -1e30f, -1e30f, -1e30f};
#pragma unroll
        for (int f = 0; f < 4; ++f) {
            int kkg = kt * 64 + f * 16 + a;
            bool valid = kkg < length;
#pragma unroll
            for (int r = 0; r < 4; ++r) {
                float v = valid ? s[f][r] * 0.125f : -1e30f;
                s[f][r] = v;
                mloc[r] = fmaxf(mloc[r], v);
            }
        }
#pragma unroll
        for (int r = 0; r < 4; ++r) {
#pragma unroll
            for (int m = 1; m < 16; m <<= 1)
                mloc[r] = fmaxf(mloc[r], __shfl_xor(mloc[r], m));
        }
        float al[4], ps[4];
#pragma unroll
        for (int r = 0; r < 4; ++r) {
            float nm = fmaxf(m_r[r], mloc[r]);
            al[r] = __expf(m_r[r] - nm);
            m_r[r] = nm;
            ps[r] = 0.f;
        }
#pragma unroll
        for (int f = 0; f < 4; ++f)
#pragma unroll
            for (int r = 0; r < 4; ++r) {
                float p = __expf(s[f][r] - m_r[r]);
                s[f][r] = p;
                ps[r] += p;
            }
#pragma unroll
        for (int r = 0; r < 4; ++r) {
#pragma unroll
            for (int m = 1; m < 16; m <<= 1) ps[r] += __shfl_xor(ps[r], m);
            l_r[r] = l_r[r] * al[r] + ps[r];
        }
#pragma unroll
        for (int df = 0; df < 4; ++df)
#pragma unroll
            for (int r = 0; r < 4; ++r) O[df][r] *= al[r];
        if (pf) {
            asm volatile("s_waitcnt vmcnt(0)" ::: "memory");
            writeV(buf ^ 1);
        }
#pragma unroll
        for (int f = 0; f < 4; ++f)
#pragma unroll
            for (int r = 0; r < 4; ++r) {
                int prow = 4 * g + r;
                int cc = (2 * f + (a >> 3)) ^ (prow & 7);
                Ps[w][prow * 64 + cc * 8 + (a & 7)] = f2bf(s[f][r]);
            }
        asm volatile("s_waitcnt lgkmcnt(0)" ::: "memory");
        __builtin_amdgcn_sched_barrier(0);
#pragma unroll
        for (int ks = 0; ks < 2; ++ks) {
            bf16x8 pf_ = ld8(&Ps[w][a * 64 + (((ks * 4 + g) ^ (a & 7)) * 8)]);
#pragma unroll
            for (int df = 0; df < 4; ++df) {
                int vrow = df * 16 + a;
                bf16x8 vf = ld8(&Vt[buf][vrow * 64 + (((ks * 4 + g) ^ (a & 7)) * 8)]);
                O[df] = MFMA16(pf_, vf, O[df]);
            }
        }
        __syncthreads();
        buf ^= 1;
    }
#pragma unroll
    for (int df = 0; df < 4; ++df) {
        int col = h * 64 + df * 16 + a;
#pragma unroll
        for (int r = 0; r < 4; ++r) {
            int row = b * 1024 + qb * 64 + w * 16 + 4 * g + r;
            av[(size_t)row * 768 + col] = f2bf(O[df][r] / l_r[r]);
        }
    }
}

// ---------------- host launcher -------------------------------------------
extern "C" void kernel_launch(void* const* d_in, const int* in_sizes, int n_in,
                              void* d_out, int out_size, void* d_ws, size_t ws_size,
                              hipStream_t stream) {
    const float* x_in = (const float*)d_in[0];
    const unsigned* pm = (const unsigned*)d_in[1];
    const float* Wq = (const float*)d_in[2];
    const float* bq = (const float*)d_in[3];
    const float* Wk = (const float*)d_in[4];
    const float* bk = (const float*)d_in[5];
    const float* Wv = (const float*)d_in[6];
    const float* bv = (const float*)d_in[7];
    const float* Wo = (const float*)d_in[8];
    const float* bo = (const float*)d_in[9];
    const float* g1 = (const float*)d_in[10];
    const float* be1 = (const float*)d_in[11];
    const float* g2 = (const float*)d_in[12];
    const float* be2 = (const float*)d_in[13];
    const float* W1 = (const float*)d_in[14];
    const float* b1 = (const float*)d_in[15];
    const float* W2 = (const float*)d_in[16];
    const float* b2 = (const float*)d_in[17];
    const float* og = (const float*)d_in[18];
    const float* ob = (const float*)d_in[19];

    char* ws = (char*)d_ws;
    u16* wall  = (u16*)(ws + 0);            // 6 layers x 9437184 u16 weights
    float* bqkv6 = (float*)(ws + 113246208);// [6][2304] f32
    int* len4  = (int*)(ws + 113301504);    // [4]
    float* xbuf = (float*)(ws + 113301760); // [4096][768] f32 residual stream
    u16* xn    = (u16*)(ws + 125884672);    // [4096][768] bf16
    u16* qkv   = (u16*)(ws + 132176128);    // [4096][2304] bf16 (V third unused)
    u16* avb   = (u16*)(ws + 151050496);    // [4096][768] bf16
    u16* ub    = (u16*)(ws + 157341952);    // [4096][3072] bf16
    u16* vT    = (u16*)(ws + 157341952);    // [768][4096] bf16, aliases ub
                                            // (vT live: qkv256 -> attn;
                                            //  ub live: ffn1 -> ffn2)

    detect_k<<<1, 256, 0, stream>>>(pm, len4);
    conv0_k<<<9216, 256, 0, stream>>>(Wq, Wk, Wv, Wo, W1, W2, bq, bk, bv,
                                      wall, bqkv6);
    for (int l = 0; l < 6; ++l) {
        u16* wl = wall + (size_t)l * 9437184u;
        const float* xcur = (l == 0) ? x_in : xbuf;
        ln_k<0><<<1024, 256, 0, stream>>>(xcur, g1 + l * 768, be1 + l * 768, xn);
        qkv256_k<<<192, 512, 0, stream>>>(xn, wl, bqkv6 + l * 2304, qkv, vT);
        attn_k<<<dim3(16, 12, 4), 256, 0, stream>>>(qkv, vT, avb, len4);
        gemm_k<1><<<dim3(8, 32, 1), 512, 0, stream>>>(
            avb, wl + 3 * 589824, bo + l * 768, xcur, xbuf, 768, 768,
            nullptr, nullptr, nullptr, nullptr, nullptr, nullptr, nullptr, 0);
        ln_k<0><<<1024, 256, 0, stream>>>(xbuf, g2 + l * 768, be2 + l * 768, xn);
        ffn1_k<<<256, 512, 0, stream>>>(xn, wl + 2359296, b1 + l * 6144, ub);
        // FFN2 hosts next layer's weight conversion in z-slices 1..18
        const int zconv = (l < 5) ? 19 : 1;
        gemm_k<1><<<dim3(8, 32, zconv), 512, 0, stream>>>(
            ub, wl + 7077888, b2 + l * 768, xbuf, xbuf, 768, 3072,
            Wq, Wk, Wv, Wo, W1, W2, wall, l + 1);
    }
    ln_k<1><<<1024, 256, 0, stream>>>(xbuf, og, ob, d_out);
}